// Round 5
// baseline (192.342 us; speedup 1.0000x reference)
//
#include <hip/hip_runtime.h>
#include <stdint.h>

#define N_BOX 1024
#define C_CLS 80
#define B_IMG 4
#define K_PER 100
#define K_TOT 300
#define NEGF  (-1e30f)
#define NWORD 16                 // 1024 bits / 64
#define NCAND (C_CLS * K_PER)    // 8000 candidates per image
#define M_SEL 8192               // flat-index packing base for final top-k

typedef unsigned long long u64;
typedef unsigned int u32;

// ---- monotone float <-> ordered-uint mapping (total order, bit-exact) ----
__device__ __forceinline__ u32 ford(float f) {
    u32 u = __float_as_uint(f);
    return (u & 0x80000000u) ? ~u : (u | 0x80000000u);
}
__device__ __forceinline__ float funord(u32 o) {
    u32 u = (o & 0x80000000u) ? (o ^ 0x80000000u) : ~o;
    return __uint_as_float(u);
}

// IoU matching the numpy/jax float32 arithmetic exactly: no fma contraction.
__device__ __forceinline__ float iou_f(float4 a, float4 b) {
#pragma clang fp contract(off)
    float y1a = fminf(a.x, a.z), y2a = fmaxf(a.x, a.z);
    float x1a = fminf(a.y, a.w), x2a = fmaxf(a.y, a.w);
    float y1b = fminf(b.x, b.z), y2b = fmaxf(b.x, b.z);
    float x1b = fminf(b.y, b.w), x2b = fmaxf(b.y, b.w);
    float ih = fminf(y2a, y2b) - fmaxf(y1a, y1b); ih = fmaxf(ih, 0.0f);
    float iw = fminf(x2a, x2b) - fmaxf(x1a, x1b); iw = fmaxf(iw, 0.0f);
    float inter = ih * iw;
    float aa = (y2a - y1a) * (x2a - x1a);
    float ab = (y2b - y1b) * (x2b - x1b);
    float uni = aa + ab - inter;
    uni = fmaxf(uni, 1e-12f);
    return inter / uni;
}

// ---------------------------------------------------------------------------
// Kernel A: per-image IoU bitmask matrix (q==1: suppression is per-image).
// Byte-identical to the proven round-2 kernel.
// ---------------------------------------------------------------------------
__global__ __launch_bounds__(256) void iou_masks(
        const float* __restrict__ boxes,    // [B, N, 1, 4]
        u64* __restrict__ masks)            // [B, N, NWORD]
{
    __shared__ float4 bx[N_BOX];            // 16 KB
    const int tid = threadIdx.x;
    const int b  = blockIdx.x >> 6;         // 4 images
    const int rg = blockIdx.x & 63;         // 64 row-groups of 16 rows

    for (int n = tid; n < N_BOX; n += 256)
        bx[n] = ((const float4*)boxes)[b * N_BOX + n];
    __syncthreads();

    const int r = tid >> 4;                 // local row 0..15
    const int w = tid & 15;                 // word 0..15
    const int i = rg * 16 + r;
    float4 a = bx[i];
    u64 m = 0;
    const int j0 = w * 64;
    for (int jj = 0; jj < 64; ++jj) {
        int j = j0 + jj;
        if (j != i && iou_f(a, bx[j]) > 0.5f) m |= (1ull << jj);
    }
    masks[((size_t)(b * N_BOX + i)) * NWORD + w] = m;
}

// ---------------------------------------------------------------------------
// Kernel B: one block per (image, class-PAIR), 512 threads. Each half (256
// thr) sorts its class's 1024 packed keys; waves 0 and 4 then run two
// independent greedy scans (round-2 PROVEN single-wave logic, verbatim).
// ---------------------------------------------------------------------------
__global__ __launch_bounds__(512) void nms_per_class(
        const float* __restrict__ scores,   // [B, N, C]
        const u64*   __restrict__ masks,    // [B, N, NWORD]
        float* __restrict__ ws_score,       // [B*C*K_PER]
        int*   __restrict__ ws_idx)         // [B*C*K_PER]
{
    __shared__ u64 key[2][N_BOX];           // 16 KB
    __shared__ int kept_t[2][K_PER];
    __shared__ int sh_nvalid[2], sh_kept[2];

    const int tid = threadIdx.x;
    const int half = tid >> 8;              // 0/1 = which class of the pair
    const int lt = tid & 255;
    const int b  = blockIdx.x / (C_CLS / 2);
    const int c0 = (blockIdx.x % (C_CLS / 2)) * 2;
    const int c  = c0 + half;

    if (lt == 0) { sh_nvalid[half] = 0; sh_kept[half] = 0; }
    __syncthreads();

    {   // strided score load (round-2 proven path; L2-resident)
        int lv = 0;
        for (int n = lt; n < N_BOX; n += 256) {
            float s = scores[(size_t)(b * N_BOX + n) * C_CLS + c];
            bool valid = s > 0.001f;                   // SCORE_THR
            float sv = valid ? s : NEGF;
            key[half][n] = ((u64)ford(sv) << 32) | (u32)(N_BOX - 1 - n);
            lv += valid ? 1 : 0;
        }
        if (lv) atomicAdd(&sh_nvalid[half], lv);
    }
    __syncthreads();

    // bitonic sort, descending; both halves share barrier flow
    u64* kk = key[half];
    for (int k = 2; k <= N_BOX; k <<= 1) {
        for (int j = k >> 1; j > 0; j >>= 1) {
            for (int i = lt; i < N_BOX; i += 256) {
                int ixj = i ^ j;
                if (ixj > i) {
                    u64 a = kk[i], q = kk[ixj];
                    if (((i & k) == 0) ? (a < q) : (a > q)) { kk[i] = q; kk[ixj] = a; }
                }
            }
            __syncthreads();
        }
    }

    // single-wave greedy (round-2 proven): wave 0 -> half 0, wave 4 -> half 1
    const int wv = tid >> 6;
    if (wv == 0 || wv == 4) {
        const int gh = wv >> 2;
        const int lane = tid & 63;
        u64 sup = 0;                         // lanes 0..15 hold suppressed words
        int kept = 0;
        const u64* mrow = masks + (size_t)b * N_BOX * NWORD;
        const u64* ks = key[gh];
        const int nvalid = sh_nvalid[gh];

        for (int bt = 0; bt < nvalid && kept < K_PER; bt += 64) {
            int t = bt + lane;
            bool in = t < nvalid;
            u64 k = ks[t & (N_BOX - 1)];
            int idx = (N_BOX - 1) - (int)(u32)(k & 0xFFFFFFFFu);  // original box id
            u64 alivemask = __ballot(in);
            while (alivemask) {
                u64 supw = __shfl(sup, idx >> 6);          // word for my box
                bool sbit = (supw >> (idx & 63)) & 1ull;
                u64 alive_now = __ballot(in && !sbit) & alivemask;
                if (!alive_now) break;                      // rest suppressed
                int t0 = __ffsll((long long)alive_now) - 1; // first kept lane
                int i0 = __shfl(idx, t0);
                if (lane == 0) kept_t[gh][kept] = bt + t0;
                kept++;
                if (kept >= K_PER) break;
                u64 roww = 0;
                if (lane < NWORD) roww = mrow[(size_t)i0 * NWORD + lane];
                sup |= roww;
                alivemask &= ~((2ull << t0) - 1ull);        // drop lanes <= t0
            }
            if (kept >= K_PER) break;
        }
        if (lane == 0) sh_kept[gh] = kept;
    }
    __syncthreads();

    const int kept = sh_kept[half];
    if (lt < K_PER) {
        int ob = (b * C_CLS + c) * K_PER + lt;
        if (lt < kept) {
            u64 k = key[half][kept_t[half][lt]];
            ws_score[ob] = funord((u32)(k >> 32));
            ws_idx[ob]   = (N_BOX - 1) - (int)(u32)(k & 0xFFFFFFFFu);
        } else {
            ws_score[ob] = NEGF;
            ws_idx[ob]   = 0;
        }
    }
}

// ---------------------------------------------------------------------------
// Kernel C: one block per image, 256 threads. u32 score keys staged in LDS
// (low 32 bits of the sort key are derived from the index, so only the score
// half is stored: 32 KB). Byte-wise MSB radix-select, 6 rounds (key bytes
// 3..2 are identically zero), with the d==7 guard restored (shift-by-64 UB
// was the round-3/4 crash). Gather exactly 300 winners; bitonic-sort 512.
// ---------------------------------------------------------------------------
__global__ __launch_bounds__(256) void final_topk(
        const float* __restrict__ ws_score,
        const int*   __restrict__ ws_idx,
        const float* __restrict__ boxes,    // [B, N, 1, 4]
        float* __restrict__ out)
{
    __shared__ u32 skey[NCAND];             // 32 KB — high word of each key
    __shared__ u32 hist[256];
    __shared__ u32 sufx[256];
    __shared__ u64 list[512];
    __shared__ int sh_sel;
    __shared__ u32 sh_need;
    __shared__ int sh_cnt, sh_valid;

    const int tid = threadIdx.x;
    const int b = blockIdx.x;
    const int base = b * NCAND;

    if (tid == 0) { sh_cnt = 0; sh_valid = 0; }
    for (int i = tid; i < NCAND; i += 256)
        skey[i] = ford(ws_score[base + i]);
    list[tid] = 0;
    list[tid + 256] = 0;
    __syncthreads();

    u64 prefix = 0;
    u32 need = K_TOT;
    const int rounds[6] = {7, 6, 5, 4, 1, 0};

    for (int rd = 0; rd < 6; ++rd) {
        const int d = rounds[rd];
        hist[tid] = 0;
        __syncthreads();
        for (int i = tid; i < NCAND; i += 256) {
            u64 k = ((u64)skey[i] << 32) | (u32)(M_SEL - 1 - i);
            // d==7 guard: shift by 64 is UB (the round-3/4 crash)
            bool match = (d == 7) || (((k ^ prefix) >> (8 * (d + 1))) == 0);
            if (match) atomicAdd(&hist[(u32)(k >> (8 * d)) & 0xFFu], 1u);
        }
        __syncthreads();
        sufx[tid] = hist[tid];
        __syncthreads();
        for (int off = 1; off < 256; off <<= 1) {   // Hillis-Steele suffix sum
            u32 add = (tid + off < 256) ? sufx[tid + off] : 0u;
            __syncthreads();
            sufx[tid] += add;
            __syncthreads();
        }
        {
            u32 sv = sufx[tid];
            u32 sn = (tid == 255) ? 0u : sufx[tid + 1];
            if (sv >= need && sn < need) { sh_sel = tid; sh_need = need - sn; }
        }
        __syncthreads();
        prefix |= ((u64)(u32)sh_sel) << (8 * d);
        need = sh_need;
        __syncthreads();
    }
    // prefix == exact key of the 300th-largest; winners: key >= prefix (exactly 300)

    for (int i = tid; i < NCAND; i += 256) {
        u64 k = ((u64)skey[i] << 32) | (u32)(M_SEL - 1 - i);
        if (k >= prefix) {
            int p = atomicAdd(&sh_cnt, 1);
            if (p < 512) list[p] = k;       // defensive clamp
        }
    }
    __syncthreads();

    // bitonic sort 512 descending (pads 0 sort last), 2 CE per thread
    for (int k2 = 2; k2 <= 512; k2 <<= 1) {
        for (int j = k2 >> 1; j > 0; j >>= 1) {
            for (int i = tid; i < 512; i += 256) {
                int ixj = i ^ j;
                if (ixj > i) {
                    u64 a = list[i], q = list[ixj];
                    if (((i & k2) == 0) ? (a < q) : (a > q)) { list[i] = q; list[ixj] = a; }
                }
            }
            __syncthreads();
        }
    }

    float* out_s = out;                         // [B,300]
    float* out_b = out + B_IMG * K_TOT;         // [B,300,4]
    float* out_c = out + B_IMG * K_TOT * 5;     // [B,300]
    float* out_n = out + B_IMG * K_TOT * 6;     // [B]

    for (int i = tid; i < K_TOT; i += 256) {
        u64 k = list[i];
        float s = funord((u32)(k >> 32));
        int flat = (M_SEL - 1) - (int)(u32)(k & 0xFFFFFFFFu);
        bool valid = s > (-5e29f);              // top_s > NEG/2
        float os = 0.0f, oc = 0.0f;
        float4 ob = make_float4(0.0f, 0.0f, 0.0f, 0.0f);
        if (valid && flat < NCAND) {
            int cc = flat / K_PER;
            int n  = ws_idx[base + flat];
            float4 bb = ((const float4*)boxes)[b * N_BOX + n];
            os = s;
            oc = (float)cc;
            ob.x = fminf(fmaxf(bb.x, 0.0f), 1.0f);
            ob.y = fminf(fmaxf(bb.y, 0.0f), 1.0f);
            ob.z = fminf(fmaxf(bb.z, 0.0f), 1.0f);
            ob.w = fminf(fmaxf(bb.w, 0.0f), 1.0f);
            atomicAdd(&sh_valid, 1);
        }
        out_s[b * K_TOT + i] = os;
        ((float4*)out_b)[b * K_TOT + i] = ob;
        out_c[b * K_TOT + i] = oc;
    }
    __syncthreads();
    if (tid == 0) out_n[b] = (float)sh_valid;
}

extern "C" void kernel_launch(void* const* d_in, const int* in_sizes, int n_in,
                              void* d_out, int out_size, void* d_ws, size_t ws_size,
                              hipStream_t stream) {
    const float* scores = (const float*)d_in[0];   // [4,1024,80]
    const float* boxes  = (const float*)d_in[1];   // [4,1024,1,4]

    // EXACT round-2 workspace layout (780,288 B proven safe).
    char* ws = (char*)d_ws;
    float* ws_score = (float*)ws;                          // 128,000 B
    int*   ws_idx   = (int*)  (ws + 128000);               // 128,000 B
    u64*   masks    = (u64*)  (ws + 256000);               // 524,288 B

    iou_masks<<<dim3(B_IMG * 64), dim3(256), 0, stream>>>(boxes, masks);
    nms_per_class<<<dim3(B_IMG * (C_CLS / 2)), dim3(512), 0, stream>>>(
        scores, masks, ws_score, ws_idx);
    final_topk<<<dim3(B_IMG), dim3(256), 0, stream>>>(
        ws_score, ws_idx, boxes, (float*)d_out);
}

// Round 6
// 179.586 us; speedup vs baseline: 1.0710x; 1.0710x over previous
//
#include <hip/hip_runtime.h>
#include <stdint.h>

#define N_BOX 1024
#define C_CLS 80
#define B_IMG 4
#define K_PER 100
#define K_TOT 300
#define NEGF  (-1e30f)
#define NWORD 16                 // 1024 bits / 64
#define NCAND (C_CLS * K_PER)    // 8000 candidates per image
#define M_SEL 8192               // flat-index packing base for final top-k

typedef unsigned long long u64;
typedef unsigned int u32;

// ---- monotone float <-> ordered-uint mapping (total order, bit-exact) ----
__device__ __forceinline__ u32 ford(float f) {
    u32 u = __float_as_uint(f);
    return (u & 0x80000000u) ? ~u : (u | 0x80000000u);
}
__device__ __forceinline__ float funord(u32 o) {
    u32 u = (o & 0x80000000u) ? (o ^ 0x80000000u) : ~o;
    return __uint_as_float(u);
}

// IoU matching the numpy/jax float32 arithmetic exactly: no fma contraction.
__device__ __forceinline__ float iou_f(float4 a, float4 b) {
#pragma clang fp contract(off)
    float y1a = fminf(a.x, a.z), y2a = fmaxf(a.x, a.z);
    float x1a = fminf(a.y, a.w), x2a = fmaxf(a.y, a.w);
    float y1b = fminf(b.x, b.z), y2b = fmaxf(b.x, b.z);
    float x1b = fminf(b.y, b.w), x2b = fmaxf(b.y, b.w);
    float ih = fminf(y2a, y2b) - fmaxf(y1a, y1b); ih = fmaxf(ih, 0.0f);
    float iw = fminf(x2a, x2b) - fmaxf(x1a, x1b); iw = fmaxf(iw, 0.0f);
    float inter = ih * iw;
    float aa = (y2a - y1a) * (x2a - x1a);
    float ab = (y2b - y1b) * (x2b - x1b);
    float uni = aa + ab - inter;
    uni = fmaxf(uni, 1e-12f);
    return inter / uni;
}

// ---------------------------------------------------------------------------
// Kernel A: per-image IoU bitmask matrix (q==1: suppression is per-image).
// Byte-identical to the proven round-2/5 kernel.
// ---------------------------------------------------------------------------
__global__ __launch_bounds__(256) void iou_masks(
        const float* __restrict__ boxes,    // [B, N, 1, 4]
        u64* __restrict__ masks)            // [B, N, NWORD]
{
    __shared__ float4 bx[N_BOX];            // 16 KB
    const int tid = threadIdx.x;
    const int b  = blockIdx.x >> 6;         // 4 images
    const int rg = blockIdx.x & 63;         // 64 row-groups of 16 rows

    for (int n = tid; n < N_BOX; n += 256)
        bx[n] = ((const float4*)boxes)[b * N_BOX + n];
    __syncthreads();

    const int r = tid >> 4;                 // local row 0..15
    const int w = tid & 15;                 // word 0..15
    const int i = rg * 16 + r;
    float4 a = bx[i];
    u64 m = 0;
    const int j0 = w * 64;
    for (int jj = 0; jj < 64; ++jj) {
        int j = j0 + jj;
        if (j != i && iou_f(a, bx[j]) > 0.5f) m |= (1ull << jj);
    }
    masks[((size_t)(b * N_BOX + i)) * NWORD + w] = m;
}

// ---------------------------------------------------------------------------
// Kernel B: one block per (image, class-PAIR), 512 threads. Each half (256
// thr) sorts its class's 1024 packed keys; waves 0 and 4 then run two
// independent BATCHED greedy scans: 4 candidate mask rows fetched per serial
// L2 round-trip (4 rows x 16 words = 64 lanes), precedence resolved
// in-register. Cuts the dependent-load chain ~110 -> ~32 round-trips.
// ---------------------------------------------------------------------------
__global__ __launch_bounds__(512) void nms_per_class(
        const float* __restrict__ scores,   // [B, N, C]
        const u64*   __restrict__ masks,    // [B, N, NWORD]
        float* __restrict__ ws_score,       // [B*C*K_PER]
        int*   __restrict__ ws_idx)         // [B*C*K_PER]
{
    __shared__ u64 key[2][N_BOX];           // 16 KB
    __shared__ int kept_t[2][K_PER];
    __shared__ int sh_nvalid[2], sh_kept[2];

    const int tid = threadIdx.x;
    const int half = tid >> 8;              // 0/1 = which class of the pair
    const int lt = tid & 255;
    const int b  = blockIdx.x / (C_CLS / 2);
    const int c0 = (blockIdx.x % (C_CLS / 2)) * 2;
    const int c  = c0 + half;

    if (lt == 0) { sh_nvalid[half] = 0; sh_kept[half] = 0; }
    __syncthreads();

    {   // strided score load (proven path; L2-resident)
        int lv = 0;
        for (int n = lt; n < N_BOX; n += 256) {
            float s = scores[(size_t)(b * N_BOX + n) * C_CLS + c];
            bool valid = s > 0.001f;                   // SCORE_THR
            float sv = valid ? s : NEGF;
            key[half][n] = ((u64)ford(sv) << 32) | (u32)(N_BOX - 1 - n);
            lv += valid ? 1 : 0;
        }
        if (lv) atomicAdd(&sh_nvalid[half], lv);
    }
    __syncthreads();

    // bitonic sort, descending; both halves share barrier flow
    u64* kk = key[half];
    for (int k = 2; k <= N_BOX; k <<= 1) {
        for (int j = k >> 1; j > 0; j >>= 1) {
            for (int i = lt; i < N_BOX; i += 256) {
                int ixj = i ^ j;
                if (ixj > i) {
                    u64 a = kk[i], q = kk[ixj];
                    if (((i & k) == 0) ? (a < q) : (a > q)) { kk[i] = q; kk[ixj] = a; }
                }
            }
            __syncthreads();
        }
    }

    // batched single-wave greedy: wave 0 -> half 0, wave 4 -> half 1
    const int wv = tid >> 6;
    if (wv == 0 || wv == 4) {
        const int gh = wv >> 2;
        const int lane = tid & 63;
        const int w16 = lane & 15;
        const int rr = lane >> 4;                     // which of 4 batch rows I load
        const u64* mrow = masks + (size_t)b * N_BOX * NWORD;
        const u64* ks = key[gh];
        const int nvalid = sh_nvalid[gh];
        u64 sup = 0;                                  // lanes 0..15 hold words
        int kept = 0;

        for (int bt = 0; bt < nvalid && kept < K_PER; bt += 64) {
            int t = bt + lane;
            bool in = t < nvalid;
            u64 kv = ks[t & (N_BOX - 1)];
            int idx = (N_BOX - 1) - (int)(u32)(kv & 0xFFFFFFFFu); // original box id
            u64 window = __ballot(in);
            while (window && kept < K_PER) {
                u64 supw = __shfl(sup, idx >> 6);
                bool sbit = (supw >> (idx & 63)) & 1ull;
                u64 alive = __ballot(in && !sbit) & window;
                if (!alive) break;
                // pick up to 4 leading alive candidates (all wave-uniform)
                int nb = 0, ts0 = 63, ts1 = 63, ts2 = 63, ts3 = 63;
                {
                    u64 am = alive;
                    ts0 = __ffsll((long long)am) - 1; am &= am - 1; nb = 1;
                    if (am) { ts1 = __ffsll((long long)am) - 1; am &= am - 1; nb = 2; }
                    if (am) { ts2 = __ffsll((long long)am) - 1; am &= am - 1; nb = 3; }
                    if (am) { ts3 = __ffsll((long long)am) - 1; nb = 4; }
                }
                int bi0 = __shfl(idx, ts0), bi1 = __shfl(idx, ts1);
                int bi2 = __shfl(idx, ts2), bi3 = __shfl(idx, ts3);
                int bir = (rr == 0) ? bi0 : (rr == 1) ? bi1 : (rr == 2) ? bi2 : bi3;
                u64 myrow = 0;
                if (rr < nb) myrow = mrow[(size_t)bir * NWORD + w16];
                // progressive accept within the batch (greedy-exact):
                // cand r is kept iff not suppressed by any ACCEPTED cand < r.
                bool acc1 = false, acc2 = false, acc3 = false;
                if (nb > 1) {
                    u64 w = __shfl(myrow, (bi1 >> 6));           // row0 words, lanes 0..15
                    acc1 = !((w >> (bi1 & 63)) & 1ull);
                }
                if (nb > 2) {
                    u64 w = __shfl(myrow, (bi2 >> 6));
                    bool s2 = (w >> (bi2 & 63)) & 1ull;
                    if (!s2 && acc1) {
                        u64 w2 = __shfl(myrow, 16 + (bi2 >> 6)); // row1 words
                        s2 = (w2 >> (bi2 & 63)) & 1ull;
                    }
                    acc2 = !s2;
                }
                if (nb > 3) {
                    u64 w = __shfl(myrow, (bi3 >> 6));
                    bool s3 = (w >> (bi3 & 63)) & 1ull;
                    if (!s3 && acc1) {
                        u64 w2 = __shfl(myrow, 16 + (bi3 >> 6));
                        s3 = (w2 >> (bi3 & 63)) & 1ull;
                    }
                    if (!s3 && acc2) {
                        u64 w2 = __shfl(myrow, 32 + (bi3 >> 6)); // row2 words
                        s3 = (w2 >> (bi3 & 63)) & 1ull;
                    }
                    acc3 = !s3;
                }
                // commit accepted in order; OR their rows into sup
                int tsv[4] = {ts0, ts1, ts2, ts3};
                bool accv[4] = {true, acc1, acc2, acc3};
                #pragma unroll
                for (int r = 0; r < 4; ++r) {
                    if (r < nb && accv[r] && kept < K_PER) {
                        if (lane == 0) kept_t[gh][kept] = bt + tsv[r];
                        kept++;
                        u64 w = __shfl(myrow, r * 16 + w16);
                        if (lane < NWORD) sup |= w;
                    }
                }
                int tlast = tsv[nb - 1];
                window &= ~((2ull << tlast) - 1ull);
            }
        }
        if (lane == 0) sh_kept[gh] = kept;
    }
    __syncthreads();

    const int kept = sh_kept[half];
    if (lt < K_PER) {
        int ob = (b * C_CLS + c) * K_PER + lt;
        if (lt < kept) {
            u64 k = key[half][kept_t[half][lt]];
            ws_score[ob] = funord((u32)(k >> 32));
            ws_idx[ob]   = (N_BOX - 1) - (int)(u32)(k & 0xFFFFFFFFu);
        } else {
            ws_score[ob] = NEGF;
            ws_idx[ob]   = 0;
        }
    }
}

// ---------------------------------------------------------------------------
// Kernel C: one block per image, 256 threads. u32 score keys staged in LDS.
// Byte-wise MSB radix-select, 6 rounds (key bytes 3..2 identically zero),
// d==7 shift-UB guard kept. 4-slot sub-histogram (quarters same-bin LDS
// atomic serialization) + wave-0 shuffle suffix-scan (3 barriers/round
// instead of ~16). Gather exactly 300 winners; bitonic-sort 512.
// ---------------------------------------------------------------------------
__global__ __launch_bounds__(256) void final_topk(
        const float* __restrict__ ws_score,
        const int*   __restrict__ ws_idx,
        const float* __restrict__ boxes,    // [B, N, 1, 4]
        float* __restrict__ out)
{
    __shared__ u32 skey[NCAND];             // 32 KB — high word of each key
    __shared__ u32 hist4[256 * 4];          // 4 KB — 4 bank-spread slots/bin
    __shared__ u64 list[512];
    __shared__ int sh_sel;
    __shared__ u32 sh_need;
    __shared__ int sh_cnt, sh_valid;

    const int tid = threadIdx.x;
    const int b = blockIdx.x;
    const int base = b * NCAND;

    if (tid == 0) { sh_cnt = 0; sh_valid = 0; }
    for (int i = tid; i < NCAND; i += 256)
        skey[i] = ford(ws_score[base + i]);
    list[tid] = 0;
    list[tid + 256] = 0;
    #pragma unroll
    for (int q = 0; q < 4; ++q) hist4[q * 256 + tid] = 0;
    __syncthreads();

    u64 prefix = 0;
    u32 need = K_TOT;
    const int rounds[6] = {7, 6, 5, 4, 1, 0};
    const int slot = tid & 3;

    for (int rd = 0; rd < 6; ++rd) {
        const int d = rounds[rd];
        for (int i = tid; i < NCAND; i += 256) {
            u64 k = ((u64)skey[i] << 32) | (u32)(M_SEL - 1 - i);
            // d==7 guard: shift by 64 is UB (the round-3/4 crash)
            bool match = (d == 7) || (((k ^ prefix) >> (8 * (d + 1))) == 0);
            if (match)
                atomicAdd(&hist4[(((u32)(k >> (8 * d)) & 0xFFu) << 2) | slot], 1u);
        }
        __syncthreads();
        // wave 0: sum slots, suffix-scan 256 bins (4 bins/lane), select, zero
        if (tid < 64) {
            const int l = tid;
            u32 h[4];
            #pragma unroll
            for (int q = 0; q < 4; ++q) {
                int bin = 4 * l + q;
                h[q] = hist4[bin * 4 + 0] + hist4[bin * 4 + 1]
                     + hist4[bin * 4 + 2] + hist4[bin * 4 + 3];
                hist4[bin * 4 + 0] = 0; hist4[bin * 4 + 1] = 0;
                hist4[bin * 4 + 2] = 0; hist4[bin * 4 + 3] = 0;
            }
            u32 s3 = h[3], s2 = h[2] + s3, s1 = h[1] + s2, s0 = h[0] + s1;
            u32 tot = s0, S = tot;
            #pragma unroll
            for (int off = 1; off < 64; off <<= 1) {
                u32 t = __shfl(S, (l + off) & 63);
                if (l + off < 64) S += t;
            }
            u32 T = S - tot;                 // suffix over lanes > l (bins >= 4l+4)
            u32 sv0 = s0 + T, sv1 = s1 + T, sv2 = s2 + T, sv3 = s3 + T;
            if (sv0 >= need && sv1 < need) { sh_sel = 4*l;     sh_need = need - sv1; }
            if (sv1 >= need && sv2 < need) { sh_sel = 4*l + 1; sh_need = need - sv2; }
            if (sv2 >= need && sv3 < need) { sh_sel = 4*l + 2; sh_need = need - sv3; }
            if (sv3 >= need && T   < need) { sh_sel = 4*l + 3; sh_need = need - T;   }
        }
        __syncthreads();
        prefix |= ((u64)(u32)sh_sel) << (8 * d);
        need = sh_need;
        __syncthreads();
    }
    // prefix == exact key of the 300th-largest; winners: key >= prefix (exactly 300)

    for (int i = tid; i < NCAND; i += 256) {
        u64 k = ((u64)skey[i] << 32) | (u32)(M_SEL - 1 - i);
        if (k >= prefix) {
            int p = atomicAdd(&sh_cnt, 1);
            if (p < 512) list[p] = k;       // defensive clamp
        }
    }
    __syncthreads();

    // bitonic sort 512 descending (pads 0 sort last), 2 CE per thread
    for (int k2 = 2; k2 <= 512; k2 <<= 1) {
        for (int j = k2 >> 1; j > 0; j >>= 1) {
            for (int i = tid; i < 512; i += 256) {
                int ixj = i ^ j;
                if (ixj > i) {
                    u64 a = list[i], q = list[ixj];
                    if (((i & k2) == 0) ? (a < q) : (a > q)) { list[i] = q; list[ixj] = a; }
                }
            }
            __syncthreads();
        }
    }

    float* out_s = out;                         // [B,300]
    float* out_b = out + B_IMG * K_TOT;         // [B,300,4]
    float* out_c = out + B_IMG * K_TOT * 5;     // [B,300]
    float* out_n = out + B_IMG * K_TOT * 6;     // [B]

    for (int i = tid; i < K_TOT; i += 256) {
        u64 k = list[i];
        float s = funord((u32)(k >> 32));
        int flat = (M_SEL - 1) - (int)(u32)(k & 0xFFFFFFFFu);
        bool valid = s > (-5e29f);              // top_s > NEG/2
        float os = 0.0f, oc = 0.0f;
        float4 ob = make_float4(0.0f, 0.0f, 0.0f, 0.0f);
        if (valid && flat < NCAND) {
            int cc = flat / K_PER;
            int n  = ws_idx[base + flat];
            float4 bb = ((const float4*)boxes)[b * N_BOX + n];
            os = s;
            oc = (float)cc;
            ob.x = fminf(fmaxf(bb.x, 0.0f), 1.0f);
            ob.y = fminf(fmaxf(bb.y, 0.0f), 1.0f);
            ob.z = fminf(fmaxf(bb.z, 0.0f), 1.0f);
            ob.w = fminf(fmaxf(bb.w, 0.0f), 1.0f);
            atomicAdd(&sh_valid, 1);
        }
        out_s[b * K_TOT + i] = os;
        ((float4*)out_b)[b * K_TOT + i] = ob;
        out_c[b * K_TOT + i] = oc;
    }
    __syncthreads();
    if (tid == 0) out_n[b] = (float)sh_valid;
}

extern "C" void kernel_launch(void* const* d_in, const int* in_sizes, int n_in,
                              void* d_out, int out_size, void* d_ws, size_t ws_size,
                              hipStream_t stream) {
    const float* scores = (const float*)d_in[0];   // [4,1024,80]
    const float* boxes  = (const float*)d_in[1];   // [4,1024,1,4]

    // EXACT round-2/5 workspace layout (780,288 B proven safe).
    char* ws = (char*)d_ws;
    float* ws_score = (float*)ws;                          // 128,000 B
    int*   ws_idx   = (int*)  (ws + 128000);               // 128,000 B
    u64*   masks    = (u64*)  (ws + 256000);               // 524,288 B

    iou_masks<<<dim3(B_IMG * 64), dim3(256), 0, stream>>>(boxes, masks);
    nms_per_class<<<dim3(B_IMG * (C_CLS / 2)), dim3(512), 0, stream>>>(
        scores, masks, ws_score, ws_idx);
    final_topk<<<dim3(B_IMG), dim3(256), 0, stream>>>(
        ws_score, ws_idx, boxes, (float*)d_out);
}